// Round 8
// baseline (237.363 us; speedup 1.0000x reference)
//
#include <hip/hip_runtime.h>

typedef short bf16x8 __attribute__((ext_vector_type(8)));
typedef float f32x4 __attribute__((ext_vector_type(4)));
typedef unsigned short u16x8 __attribute__((ext_vector_type(8)));

static __device__ __forceinline__ unsigned short f2bf(float f) {
  unsigned int x = __builtin_bit_cast(unsigned int, f);
  x += 0x7FFFu + ((x >> 16) & 1u);   // RNE
  return (unsigned short)(x >> 16);
}
// pack two floats' bf16 (round-half-up) into one u32 (lo=a, hi=b)
static __device__ __forceinline__ unsigned int pk2bf(float a, float b) {
  unsigned int ia = __builtin_bit_cast(unsigned int, a) + 0x8000u;
  unsigned int ib = __builtin_bit_cast(unsigned int, b) + 0x8000u;
  return __builtin_amdgcn_perm(ib, ia, 0x07060302u);
}
// async 16B global -> LDS
static __device__ __forceinline__ void gl2lds16(const unsigned short* g, unsigned short* l) {
  __builtin_amdgcn_global_load_lds(
      (const __attribute__((address_space(1))) unsigned int*)g,
      (__attribute__((address_space(3))) unsigned int*)l, 16, 0, 0);
}

// ---- prep: merged cvt3 (q/k/v fp32 -> packed xbf[8192][1536]) + wtrans4 ----
__global__ __launch_bounds__(256) void prep(const float* __restrict__ q, const float* __restrict__ k,
                                            const float* __restrict__ v,
                                            const float* __restrict__ Wq, const float* __restrict__ Wk,
                                            const float* __restrict__ Wv, const float* __restrict__ Wo,
                                            unsigned short* __restrict__ xbf,
                                            unsigned short* __restrict__ WT) {
  __shared__ __align__(16) float T[64 * 68];
  const int bid = blockIdx.x;
  const int tid = threadIdx.x;
  if (bid < 6144) {
    const int sec = bid / 2048;
    const float* src = (sec == 0) ? q : (sec == 1) ? k : v;
    int i = ((bid % 2048) * 256 + tid) * 8;
    int row = i >> 9, col = i & 511;
    float4 a = *(const float4*)(src + i);
    float4 b = *(const float4*)(src + i + 4);
    uint4 pk;
    pk.x = pk2bf(a.x, a.y); pk.y = pk2bf(a.z, a.w);
    pk.z = pk2bf(b.x, b.y); pk.w = pk2bf(b.z, b.w);
    *(uint4*)(xbf + (size_t)row * 1536 + sec * 512 + col) = pk;
  } else {
    const int w = bid - 6144;            // 0..255
    const int z = w >> 6;
    const float* W = (z == 0) ? Wq : (z == 1) ? Wk : (z == 2) ? Wv : Wo;
    unsigned short* out = WT + (size_t)z * 512 * 512;
    const int k0 = ((w >> 3) & 7) * 64, n0 = (w & 7) * 64;
#pragma unroll
    for (int i = 0; i < 4; ++i) {
      int chunk = i * 256 + tid;
      int row = chunk >> 4, fc = chunk & 15;
      *(float4*)(T + row * 68 + fc * 4) =
          *(const float4*)(W + (size_t)(k0 + row) * 512 + n0 + fc * 4);
    }
    __syncthreads();
#pragma unroll
    for (int i = 0; i < 2; ++i) {
      int chunk = i * 256 + tid;
      int nr = chunk >> 3, kc = chunk & 7;
      u16x8 vv;
#pragma unroll
      for (int j = 0; j < 8; ++j) vv[j] = f2bf(T[(kc * 8 + j) * 68 + nr]);
      *(u16x8*)(out + (size_t)(n0 + nr) * 512 + k0 + kc * 8) = vv;
    }
  }
}

// ---- fused QKV GEMM: C[8192][1536]. 128x128 tile, BK=32, 4x4 acc/wave, async dbuf. ----
__global__ __launch_bounds__(256) void gemm_qkv(const unsigned short* __restrict__ xbf,
                                                const unsigned short* __restrict__ Bt,
                                                unsigned short* __restrict__ C,
                                                float qscale) {
  __shared__ __align__(16) unsigned short Abuf[2][128 * 32];
  __shared__ __align__(16) unsigned short Bbuf[2][128 * 32];
  const int by = blockIdx.y;
  const unsigned short* A = xbf + (by >> 2) * 512;
  const float scale = (by < 4) ? qscale : 1.0f;
  const int tid = threadIdx.x;
  const int wid = tid >> 6, lane = tid & 63, quad = lane >> 4, li = lane & 15;
  const int bm = blockIdx.x * 128, bn = by * 128;
  const int wm = (wid & 1) * 64, wn = (wid >> 1) * 64;
  const unsigned short* ga[2]; int oa[2];
  const unsigned short* gb[2]; int obx[2];
#pragma unroll
  for (int i = 0; i < 2; ++i) {
    int lam = i * 256 + tid;
    int r = lam >> 2, c = (lam & 3) ^ (r & 3);
    ga[i] = A + (size_t)(bm + r) * 1536 + c * 8;
    oa[i] = lam * 8;
    gb[i] = Bt + (size_t)(bn + r) * 512 + c * 8;
    obx[i] = lam * 8;
  }
#pragma unroll
  for (int i = 0; i < 2; ++i) {
    gl2lds16(ga[i], &Abuf[0][oa[i]]); ga[i] += 32;
    gl2lds16(gb[i], &Bbuf[0][obx[i]]); gb[i] += 32;
  }
  f32x4 acc[4][4] = {};
  const int sw = li & 3;
  for (int s = 0; s < 16; ++s) {
    __syncthreads();
    if (s + 1 < 16) {
      int p = (s + 1) & 1;
#pragma unroll
      for (int i = 0; i < 2; ++i) {
        gl2lds16(ga[i], &Abuf[p][oa[i]]); ga[i] += 32;
        gl2lds16(gb[i], &Bbuf[p][obx[i]]); gb[i] += 32;
      }
    }
    const unsigned short* As = &Abuf[s & 1][0];
    const unsigned short* Bs = &Bbuf[s & 1][0];
    bf16x8 af[4], bfr[4];
#pragma unroll
    for (int t = 0; t < 4; ++t) {
      af[t]  = *(const bf16x8*)(As + (wm + t * 16 + li) * 32 + ((quad ^ sw) * 8));
      bfr[t] = *(const bf16x8*)(Bs + (wn + t * 16 + li) * 32 + ((quad ^ sw) * 8));
    }
#pragma unroll
    for (int mt = 0; mt < 4; ++mt)
#pragma unroll
      for (int nt = 0; nt < 4; ++nt)
        acc[mt][nt] = __builtin_amdgcn_mfma_f32_16x16x32_bf16(af[mt], bfr[nt], acc[mt][nt], 0, 0, 0);
  }
#pragma unroll
  for (int mt = 0; mt < 4; ++mt)
#pragma unroll
    for (int nt = 0; nt < 4; ++nt) {
      int r0 = bm + wm + mt * 16 + quad * 4;
      int c  = bn + wn + nt * 16 + li;
#pragma unroll
      for (int r = 0; r < 4; ++r)
        C[(size_t)(r0 + r) * 1536 + c] = f2bf(acc[mt][nt][r] * scale);
    }
}

// ---- kvfrag: pack K into A-frag order, V into B-frag order, per 64-key tile.
// K-frag fi=kb*2+dh: lane l, j=0..7 -> K[kb*16+(l&15)][(l>>4)*8+dh*32+j]
// V-frag fi=dc*2+kh: lane l, j=0..7 -> V[(l>>4)*8+kh*32+j][dc*16+(l&15)]
// Arrays: [(bh*64+kt)*8 + fi][lane][8] ushorts (1KB per frag, coalesced reads in attn). ----
__global__ __launch_bounds__(512) void kvfrag(const unsigned short* __restrict__ qkv,
                                              unsigned short* __restrict__ kfr,
                                              unsigned short* __restrict__ vfr) {
  __shared__ __align__(16) unsigned short Ksh[64 * 72];
  __shared__ __align__(16) unsigned short Vsh[64 * 72];
  const int kt = blockIdx.x, bh = blockIdx.y;
  const int b = bh >> 3, h = bh & 7;
  const int tid = threadIdx.x;
  {
    int row = tid >> 3, c8 = tid & 7;
    const unsigned short* src = qkv + (size_t)(b * 4096 + kt * 64 + row) * 1536 + h * 64 + c8 * 8;
    *(uint4*)(Ksh + row * 72 + c8 * 8) = *(const uint4*)(src + 512);
    *(uint4*)(Vsh + row * 72 + c8 * 8) = *(const uint4*)(src + 1024);
  }
  __syncthreads();
  const int fi = tid >> 6, l = tid & 63;
  const size_t obase = ((size_t)(bh * 64 + kt) * 8 + fi) * 512 + l * 8;
  {
    int kb = fi >> 1, dh = fi & 1;
    uint4 kf = *(const uint4*)(Ksh + (kb * 16 + (l & 15)) * 72 + (l >> 4) * 8 + dh * 32);
    *(uint4*)(kfr + obase) = kf;
  }
  {
    int dc = fi >> 1, kh = fi & 1;
    u16x8 vf;
#pragma unroll
    for (int j = 0; j < 8; ++j)
      vf[j] = Vsh[((l >> 4) * 8 + kh * 32 + j) * 72 + dc * 16 + (l & 15)];
    *(u16x8*)(vfr + obase) = vf;
  }
}

// ---- barrier-free split-K flash attention: 8 waves x 32q (2 q-sets), 256q/block.
// K/V via coalesced global frag loads (no LDS staging, no per-tile barriers);
// P via per-wave LDS; no-max softmax; l-via-ones-MFMA; fp32 partials + Lb. ----
__global__ __launch_bounds__(512, 4) void attn(const unsigned short* __restrict__ qkv,
                                               const unsigned short* __restrict__ kfr,
                                               const unsigned short* __restrict__ vfr,
                                               const int* __restrict__ mask,
                                               float* __restrict__ O0, float* __restrict__ O1,
                                               float* __restrict__ Lb) {
  __shared__ __align__(16) unsigned short Psh[8][32 * 72];   // 36 KB
  __shared__ __align__(16) unsigned short MskBits[256];
  const int qt = blockIdx.x, h = blockIdx.y, z = blockIdx.z;
  const int b = z >> 1, half = z & 1;
  const int t0 = half * 32;
  const int tid = threadIdx.x;
  const int wid = tid >> 6, lane = tid & 63, quad = lane >> 4, li = lane & 15;
  const size_t tok0 = (size_t)b * 4096;
  const int bh = b * 8 + h;

  if (tid < 256) {
    const int4* mp = (const int4*)(mask + b * 4096 + tid * 16);
    unsigned int bits = 0;
#pragma unroll
    for (int j = 0; j < 4; ++j) {
      int4 m4 = mp[j];
      bits |= (m4.x ? 1u : 0u) << (j * 4 + 0);
      bits |= (m4.y ? 1u : 0u) << (j * 4 + 1);
      bits |= (m4.z ? 1u : 0u) << (j * 4 + 2);
      bits |= (m4.w ? 1u : 0u) << (j * 4 + 3);
    }
    MskBits[tid] = (unsigned short)bits;
  }
  __syncthreads();   // the only block-wide barrier

  // two Q B-operand sets per wave: rows qt*256 + wid*32 + {li, li+16}
  const unsigned short* qpa = qkv + (tok0 + qt * 256 + wid * 32 + li) * 1536 + h * 64;
  const unsigned short* qpb = qpa + 16 * 1536;
  bf16x8 bq0a = *(const bf16x8*)(qpa + quad * 8);
  bf16x8 bq1a = *(const bf16x8*)(qpa + 32 + quad * 8);
  bf16x8 bq0b = *(const bf16x8*)(qpb + quad * 8);
  bf16x8 bq1b = *(const bf16x8*)(qpb + 32 + quad * 8);

  const unsigned short* kbp = kfr + ((size_t)(bh * 64 + t0) * 8) * 512 + lane * 8;
  const unsigned short* vbp = vfr + ((size_t)(bh * 64 + t0) * 8) * 512 + lane * 8;

  f32x4 accOa[4] = {}, accOb[4] = {};
  f32x4 accLa = {}, accLb = {};
  bf16x8 bones;
#pragma unroll
  for (int j = 0; j < 8; ++j) bones[j] = (short)0x3F80;  // bf16 1.0
  unsigned short* Pw = &Psh[wid][0];

  for (int tt = 0; tt < 32; ++tt) {
    const int t = t0 + tt;
    // load 8 K-frags (coalesced dwordx4, SGPR-base + imm-friendly offsets)
    bf16x8 kf[8];
#pragma unroll
    for (int fi = 0; fi < 8; ++fi) kf[fi] = *(const bf16x8*)(kbp + fi * 512);
    // S^T = K Q^T for both q-sets; K frags shared
    f32x4 sa[4], sb[4];
#pragma unroll
    for (int kb = 0; kb < 4; ++kb) {
      f32x4 za = {}, zb = {};
      za = __builtin_amdgcn_mfma_f32_16x16x32_bf16(kf[kb * 2], bq0a, za, 0, 0, 0);
      za = __builtin_amdgcn_mfma_f32_16x16x32_bf16(kf[kb * 2 + 1], bq1a, za, 0, 0, 0);
      zb = __builtin_amdgcn_mfma_f32_16x16x32_bf16(kf[kb * 2], bq0b, zb, 0, 0, 0);
      zb = __builtin_amdgcn_mfma_f32_16x16x32_bf16(kf[kb * 2 + 1], bq1b, zb, 0, 0, 0);
      sa[kb] = za; sb[kb] = zb;
    }
    unsigned long long mbits = *(const unsigned long long*)(MskBits + t * 4);
    if (mbits != ~0ull) {
#pragma unroll
      for (int kb = 0; kb < 4; ++kb)
#pragma unroll
        for (int r = 0; r < 4; ++r) {
          int key = kb * 16 + quad * 4 + r;
          if (!((mbits >> key) & 1ull)) { sa[kb][r] = -1e30f; sb[kb][r] = -1e30f; }
        }
    }
    // p = exp2(s); pack bf16 into per-wave P
#pragma unroll
    for (int kb = 0; kb < 4; ++kb) {
#pragma unroll
      for (int r = 0; r < 4; ++r) {
        sa[kb][r] = __builtin_amdgcn_exp2f(sa[kb][r]);
        sb[kb][r] = __builtin_amdgcn_exp2f(sb[kb][r]);
      }
      uint2 pka, pkb;
      pka.x = pk2bf(sa[kb][0], sa[kb][1]); pka.y = pk2bf(sa[kb][2], sa[kb][3]);
      pkb.x = pk2bf(sb[kb][0], sb[kb][1]); pkb.y = pk2bf(sb[kb][2], sb[kb][3]);
      *(uint2*)(Pw + li * 72 + kb * 16 + quad * 4) = pka;
      *(uint2*)(Pw + (li + 16) * 72 + kb * 16 + quad * 4) = pkb;
    }
    // read P as A-frags (wave-private; lgkmcnt only, no barrier)
    bf16x8 p0a = *(const bf16x8*)(Pw + li * 72 + quad * 8);
    bf16x8 p1a = *(const bf16x8*)(Pw + li * 72 + 32 + quad * 8);
    bf16x8 p0b = *(const bf16x8*)(Pw + (li + 16) * 72 + quad * 8);
    bf16x8 p1b = *(const bf16x8*)(Pw + (li + 16) * 72 + 32 + quad * 8);
    // O += P V ; l += P * ones  (V frags via global, shared across q-sets)
#pragma unroll
    for (int dc = 0; dc < 4; ++dc) {
      bf16x8 bv0 = *(const bf16x8*)(vbp + (dc * 2) * 512);
      bf16x8 bv1 = *(const bf16x8*)(vbp + (dc * 2 + 1) * 512);
      accOa[dc] = __builtin_amdgcn_mfma_f32_16x16x32_bf16(p0a, bv0, accOa[dc], 0, 0, 0);
      accOa[dc] = __builtin_amdgcn_mfma_f32_16x16x32_bf16(p1a, bv1, accOa[dc], 0, 0, 0);
      accOb[dc] = __builtin_amdgcn_mfma_f32_16x16x32_bf16(p0b, bv0, accOb[dc], 0, 0, 0);
      accOb[dc] = __builtin_amdgcn_mfma_f32_16x16x32_bf16(p1b, bv1, accOb[dc], 0, 0, 0);
    }
    accLa = __builtin_amdgcn_mfma_f32_16x16x32_bf16(p0a, bones, accLa, 0, 0, 0);
    accLa = __builtin_amdgcn_mfma_f32_16x16x32_bf16(p1a, bones, accLa, 0, 0, 0);
    accLb = __builtin_amdgcn_mfma_f32_16x16x32_bf16(p0b, bones, accLb, 0, 0, 0);
    accLb = __builtin_amdgcn_mfma_f32_16x16x32_bf16(p1b, bones, accLb, 0, 0, 0);
    kbp += 8 * 512;
    vbp += 8 * 512;
  }
  // epilogue: unnormalized fp32 partials + l (accL rows align with accO rows)
  float* Oh = half ? O1 : O0;
  const size_t rqa = tok0 + qt * 256 + wid * 32 + quad * 4;
  const size_t rqb = rqa + 16;
#pragma unroll
  for (int dc = 0; dc < 4; ++dc) {
    size_t col = h * 64 + dc * 16 + li;
#pragma unroll
    for (int r = 0; r < 4; ++r) {
      Oh[(rqa + r) * 512 + col] = accOa[dc][r];
      Oh[(rqb + r) * 512 + col] = accOb[dc][r];
    }
  }
  if (li == 0) {
#pragma unroll
    for (int r = 0; r < 4; ++r) {
      Lb[((size_t)half * 8192 + rqa + r) * 8 + h] = accLa[r];
      Lb[((size_t)half * 8192 + rqb + r) * 8 + h] = accLb[r];
    }
  }
}

// ---- combine: ob = (O0+O1)/(l0+l1), bf16 ----
__global__ __launch_bounds__(256) void cmb(const float* __restrict__ O0, const float* __restrict__ O1,
                                           const float* __restrict__ Lb,
                                           unsigned short* __restrict__ ob) {
  int idx = (blockIdx.x * 256 + threadIdx.x) * 4;
  int tok = idx >> 9, h = (idx >> 6) & 7;
  float inv = 1.f / (Lb[(size_t)tok * 8 + h] + Lb[(size_t)(8192 + tok) * 8 + h]);
  float4 a = *(const float4*)(O0 + idx);
  float4 b = *(const float4*)(O1 + idx);
  uint2 pk;
  pk.x = pk2bf((a.x + b.x) * inv, (a.y + b.y) * inv);
  pk.y = pk2bf((a.z + b.z) * inv, (a.w + b.w) * inv);
  *(uint2*)(ob + idx) = pk;
}

// ---- O-proj GEMM: out[8192][512] f32 = ob * woT^T. 128x64, BK=64, dbuf. ----
__global__ __launch_bounds__(256) void gemm_o(const unsigned short* __restrict__ A,
                                              const unsigned short* __restrict__ Bt,
                                              float* __restrict__ Cf) {
  __shared__ __align__(16) unsigned short Abuf[2][128 * 64];
  __shared__ __align__(16) unsigned short Bbuf[2][64 * 64];
  const int K = 512, LDC = 512;
  const int tid = threadIdx.x;
  const int wid = tid >> 6, lane = tid & 63, quad = lane >> 4, li = lane & 15;
  const int bm = blockIdx.x * 128, bn = blockIdx.y * 64;
  const int wm = wid * 32;
  const unsigned short* ga[4]; int oa[4];
  const unsigned short* gb[2]; int ob[2];
#pragma unroll
  for (int i = 0; i < 4; ++i) {
    int lam = i * 256 + wid * 64 + lane;
    int r = lam >> 3, c = (lam & 7) ^ (r & 7);
    ga[i] = A + (size_t)(bm + r) * K + c * 8;
    oa[i] = lam * 8;
  }
#pragma unroll
  for (int i = 0; i < 2; ++i) {
    int lam = i * 256 + wid * 64 + lane;
    int r = lam >> 3, c = (lam & 7) ^ (r & 7);
    gb[i] = Bt + (size_t)(bn + r) * K + c * 8;
    ob[i] = lam * 8;
  }
#pragma unroll
  for (int i = 0; i < 4; ++i) { gl2lds16(ga[i], &Abuf[0][oa[i]]); ga[i] += 64; }
#pragma unroll
  for (int i = 0; i < 2; ++i) { gl2lds16(gb[i], &Bbuf[0][ob[i]]); gb[i] += 64; }

  f32x4 acc[2][4] = {};
  const int sw = li & 7;
  for (int s = 0; s < 8; ++s) {
    __syncthreads();
    if (s + 1 < 8) {
      int p = (s + 1) & 1;
#pragma unroll
      for (int i = 0; i < 4; ++i) { gl2lds16(ga[i], &Abuf[p][oa[i]]); ga[i] += 64; }
#pragma unroll
      for (int i = 0; i < 2; ++i) { gl2lds16(gb[i], &Bbuf[p][ob[i]]); gb[i] += 64; }
    }
    const unsigned short* As = &Abuf[s & 1][0];
    const unsigned short* Bs = &Bbuf[s & 1][0];
#pragma unroll
    for (int kk = 0; kk < 2; ++kk) {
      bf16x8 af[2], bfr[4];
#pragma unroll
      for (int t = 0; t < 2; ++t)
        af[t] = *(const bf16x8*)(As + (wm + t * 16 + li) * 64 + (((kk * 4 + quad) ^ sw) * 8));
#pragma unroll
      for (int t = 0; t < 4; ++t)
        bfr[t] = *(const bf16x8*)(Bs + (t * 16 + li) * 64 + (((kk * 4 + quad) ^ sw) * 8));
#pragma unroll
      for (int mt = 0; mt < 2; ++mt)
#pragma unroll
        for (int nt = 0; nt < 4; ++nt)
          acc[mt][nt] = __builtin_amdgcn_mfma_f32_16x16x32_bf16(af[mt], bfr[nt], acc[mt][nt], 0, 0, 0);
    }
  }
#pragma unroll
  for (int mt = 0; mt < 2; ++mt)
#pragma unroll
    for (int nt = 0; nt < 4; ++nt) {
      int r0 = bm + wm + mt * 16 + quad * 4;
      int c  = bn + nt * 16 + li;
#pragma unroll
      for (int r = 0; r < 4; ++r)
        Cf[(size_t)(r0 + r) * LDC + c] = acc[mt][nt][r];
    }
}

extern "C" void kernel_launch(void* const* d_in, const int* in_sizes, int n_in,
                              void* d_out, int out_size, void* d_ws, size_t ws_size,
                              hipStream_t stream) {
  const float* q  = (const float*)d_in[0];
  const float* k  = (const float*)d_in[1];
  const float* v  = (const float*)d_in[2];
  const int* mask = (const int*)d_in[3];
  const float* Wq = (const float*)d_in[4];
  const float* Wk = (const float*)d_in[5];
  const float* Wv = (const float*)d_in[6];
  const float* Wo = (const float*)d_in[7];
  float* out = (float*)d_out;

  char* ws = (char*)d_ws;
  const size_t MB = 1024 * 1024;
  // Arena (~91 MB), time-sliced:
  //  [0,16)   kfr (written by kvfrag)  ... obb at [0,8) after attn (kfr dead post-attn)
  //  [16,32)  vfr
  //  [32,56)  qkvh
  //  [56,80)  xbf (dead after gemm_qkv) -> O0 [56,72), O1 [72,88)
  //  [88,88.5) Lb
  //  [89,91)  wAll
  unsigned short* kfr  = (unsigned short*)(ws);
  unsigned short* vfr  = (unsigned short*)(ws + 16 * MB);
  unsigned short* qkvh = (unsigned short*)(ws + 32 * MB);
  unsigned short* xbf  = (unsigned short*)(ws + 56 * MB);
  float* O0f = (float*)(ws + 56 * MB);
  float* O1f = (float*)(ws + 72 * MB);
  float* Lb  = (float*)(ws + 88 * MB);
  unsigned short* wAll = (unsigned short*)(ws + 89 * MB);
  unsigned short* woT  = wAll + (size_t)3 * 512 * 512;
  unsigned short* obb  = (unsigned short*)(ws);   // over kfr, post-attn

  prep<<<6400, 256, 0, stream>>>(q, k, v, Wq, Wk, Wv, Wo, xbf, wAll);
  const float qscale = 0.125f * 1.44269504f;  // 1/sqrt(64) * log2(e)
  dim3 gq(64, 12);
  gemm_qkv<<<gq, 256, 0, stream>>>(xbf, wAll, qkvh, qscale);
  dim3 fg(64, 16);
  kvfrag<<<fg, 512, 0, stream>>>(qkvh, kfr, vfr);
  dim3 ag(16, 8, 4);
  attn<<<ag, 512, 0, stream>>>(qkvh, kfr, vfr, mask, O0f, O1f, Lb);
  cmb<<<4096, 256, 0, stream>>>(O0f, O1f, Lb, obb);
  dim3 go(64, 8);
  gemm_o<<<go, 256, 0, stream>>>(obb, woT, out);
}